// Round 4
// baseline (140.065 us; speedup 1.0000x reference)
//
#include <hip/hip_runtime.h>
#include <math.h>

#define BB 8
#define CC 512
#define LL 1024
#define GG 32
#define CPG 16
#define NH 8
#define CH 64

typedef unsigned short ushort_t;
typedef __attribute__((ext_vector_type(8))) short short8;
typedef __attribute__((ext_vector_type(4))) float f32x4;
typedef __attribute__((ext_vector_type(16))) float f32x16;

#define SCALE_Q 0.18033688f  // 0.125 * log2(e)

__device__ inline ushort_t f2bf(float f) {
  union { float f; unsigned u; } v;
  v.f = f;
  unsigned r = v.u + 0x7FFFu + ((v.u >> 16) & 1u);
  return (ushort_t)(r >> 16);
}

// pack two f32 -> two bf16 (truncate) in one v_perm_b32
__device__ inline unsigned pack_bf2(float lo, float hi) {
  return __builtin_amdgcn_perm(__float_as_uint(hi), __float_as_uint(lo),
                               0x07060302u);
}

// XOR-swizzled LDS index: rows of 64 bf16, 8-elt groups swizzled by row&7.
__device__ inline int swz(int r, int k) {
  return r * 64 + ((((k >> 3) ^ (r & 7)) << 3) | (k & 7));
}

// async 16B global->LDS (DMA). LDS dest = wave-uniform base + lane*16.
__device__ __forceinline__ void g2l16(const void* g, void* l) {
  __builtin_amdgcn_global_load_lds((const unsigned int*)g, (unsigned int*)l,
                                   16, 0, 0);
}

// ------- fused GroupNorm (stats + apply + transpose) AND weight convert ----
// blocks [0,256): one (b,g) each — x slice kept in registers between phases.
// blocks [256,768): fp32->bf16 convert of qkv_w/proj_w to pre-swizzled image.
__global__ __launch_bounds__(512) void gnx_kernel(
    const float* __restrict__ x, const float* __restrict__ gn_w,
    const float* __restrict__ gn_b, const float* __restrict__ qkv_w,
    const float* __restrict__ proj_w, ushort_t* __restrict__ xnT,
    ushort_t* __restrict__ wq, ushort_t* __restrict__ wp) {
  if (blockIdx.x < BB * GG) {
    const int b = blockIdx.x / GG;
    const int g = blockIdx.x % GG;
    const int tid = threadIdx.x;
    const int ch = tid >> 5;    // 0..15 channel within group
    const int lseg = tid & 31;  // 32-l segment
    // LDS transpose buffer: rows of 32 ushorts (4 slots x 8ch), slot rotated
    // by key(l) to spread banks on scalar writes AND uint4 reads.
    __shared__ ushort_t Ts[1024 * 32];
    __shared__ float red[16];
    __shared__ float st[2];
    const float* xc = x + ((size_t)b * CC + (size_t)g * CPG + ch) * LL;
    float4 v[8];
    float sum = 0.f, sq = 0.f;
#pragma unroll
    for (int i = 0; i < 8; ++i) {
      v[i] = *(const float4*)(xc + lseg * 32 + i * 4);
      sum += (v[i].x + v[i].y) + (v[i].z + v[i].w);
      sq += (v[i].x * v[i].x + v[i].y * v[i].y) +
            (v[i].z * v[i].z + v[i].w * v[i].w);
    }
#pragma unroll
    for (int off = 32; off > 0; off >>= 1) {
      sum += __shfl_down(sum, off);
      sq += __shfl_down(sq, off);
    }
    const int wave = tid >> 6;
    if ((tid & 63) == 0) {
      red[wave] = sum;
      red[8 + wave] = sq;
    }
    __syncthreads();
    if (tid == 0) {
      float s = 0.f, q = 0.f;
#pragma unroll
      for (int i = 0; i < 8; ++i) {
        s += red[i];
        q += red[8 + i];
      }
      float mean = s * (1.f / (CPG * LL));
      float var = q * (1.f / (CPG * LL)) - mean * mean;
      st[0] = mean;
      st[1] = rsqrtf(var + 1e-5f);
    }
    __syncthreads();
    const int c = g * CPG + ch;
    const float sc = st[1] * gn_w[c];
    const float sh = gn_b[c] - st[0] * sc;
    const int chG = ch >> 3, ch7 = ch & 7;
    // normalize from registers -> bf16 -> LDS (transposed, slot-rotated)
#pragma unroll
    for (int i = 0; i < 8; ++i) {
      float vv[4] = {v[i].x, v[i].y, v[i].z, v[i].w};
#pragma unroll
      for (int j = 0; j < 4; ++j) {
        int l = lseg * 32 + i * 4 + j;
        int key = ((l >> 5) + (l >> 2)) & 3;
        int slot = (chG + key) & 3;
        Ts[l * 32 + slot * 8 + ch7] = f2bf(vv[j] * sc + sh);
      }
    }
    __syncthreads();
    // read back uint4 (8 ch at fixed l), write pre-swizzled xnT image
    const int cb64 = (g >> 2) * 64;  // 64-col block base
    const int grpb = (g & 3) * 2;    // 8-col group base within block
#pragma unroll
    for (int it = 0; it < 4; ++it) {
      int idx = tid + it * 512;
      int l = idx >> 1, gsel = idx & 1;
      int key = ((l >> 5) + (l >> 2)) & 3;
      int slot = (gsel + key) & 3;
      uint4 val = *(const uint4*)&Ts[l * 32 + slot * 8];
      int grp = (grpb + gsel) ^ (l & 7);
      *(uint4*)(xnT + ((size_t)b * LL + l) * CC + cb64 + grp * 8) = val;
    }
  } else {
    int cb = blockIdx.x - BB * GG;
    int idx = (cb * 512 + threadIdx.x) * 4;
    const int N1 = 3 * CC * CC;
    float4 v;
    ushort_t* mat;
    int row, k;
    if (idx < N1) {
      v = *(const float4*)(qkv_w + idx);
      row = idx >> 9;
      k = idx & 511;
      mat = wq + (size_t)row * CC;
    } else {
      int j = idx - N1;
      v = *(const float4*)(proj_w + j);
      row = j >> 9;
      k = j & 511;
      mat = wp + (size_t)row * CC;
    }
    int dcol = (k & ~63) | ((((k >> 3) & 7) ^ (row & 7)) << 3) | (k & 7);
    unsigned lo = f2bf(v.x) | ((unsigned)f2bf(v.y) << 16);
    unsigned hi = f2bf(v.z) | ((unsigned)f2bf(v.w) << 16);
    *(uint2*)(mat + dcol) = make_uint2(lo, hi);
  }
}

// ---------------- QKV GEMM: 192x128 tile, 6 waves, 2-phase dbuf DMA --------
__global__ __launch_bounds__(384, 3) void qkv_mfma_kernel(
    const ushort_t* __restrict__ wq, const ushort_t* __restrict__ xnT,
    const float* __restrict__ qkv_b, ushort_t* __restrict__ qT,
    ushort_t* __restrict__ kT, ushort_t* __restrict__ vbuf) {
  const int b = blockIdx.z;
  const int m0 = blockIdx.y * 192;
  const int n0 = blockIdx.x * 128;
  const int tid = threadIdx.x;
  const int w = tid >> 6, lane = tid & 63;
  const int col = lane & 15, quad = lane >> 4;
  const int wm = (w >> 1) * 64, wn = (w & 1) * 64;
  __shared__ ushort_t Smem[2 * 20480];
  f32x4 acc[4][4];
  f32x4 z = {0.f, 0.f, 0.f, 0.f};
#pragma unroll
  for (int i = 0; i < 4; ++i)
#pragma unroll
    for (int j = 0; j < 4; ++j) acc[i][j] = z;

  const ushort_t* arow = wq + (size_t)m0 * CC;
  const ushort_t* brow = xnT + ((size_t)b * LL + n0) * CC;

  auto stage = [&](int bb, int k0) {
    ushort_t* As = Smem + bb * 20480;
    ushort_t* Bs = As + 12288;
#pragma unroll
    for (int j = 0; j < 4; ++j) {
      int e = (j * 6 + w) * 512 + lane * 8;
      g2l16(arow + (size_t)(e >> 6) * CC + k0 + (e & 63),
            As + (j * 6 + w) * 512);
    }
    if (w < 4) {
#pragma unroll
      for (int j = 0; j < 4; ++j) {
        int e = (j * 4 + w) * 512 + lane * 8;
        g2l16(brow + (size_t)(e >> 6) * CC + k0 + (e & 63),
              Bs + (j * 4 + w) * 512);
      }
    }
  };

  stage(0, 0);
  __syncthreads();
  int cur = 0;
  for (int step = 0; step < 8; ++step) {
    if (step < 7) stage(cur ^ 1, (step + 1) * 64);
    const ushort_t* As = Smem + cur * 20480;
    const ushort_t* Bs = As + 12288;
#pragma unroll
    for (int kk = 0; kk < 2; ++kk) {
      short8 af[4], bf[4];
#pragma unroll
      for (int mi = 0; mi < 4; ++mi)
        af[mi] = *(const short8*)&As[swz(wm + mi * 16 + col, kk * 32 + quad * 8)];
#pragma unroll
      for (int ni = 0; ni < 4; ++ni)
        bf[ni] = *(const short8*)&Bs[swz(wn + ni * 16 + col, kk * 32 + quad * 8)];
#pragma unroll
      for (int mi = 0; mi < 4; ++mi)
#pragma unroll
        for (int ni = 0; ni < 4; ++ni)
          acc[mi][ni] = __builtin_amdgcn_mfma_f32_16x16x32_bf16(
              af[mi], bf[ni], acc[mi][ni], 0, 0, 0);
    }
    __syncthreads();
    cur ^= 1;
  }
  // ---- epilogue: wave pair (w>>1) writes chunk ci = w>>1 (0=q,1=k,2=v) ----
  const int ci_w = w >> 1;
  ushort_t* Tile = Smem + ci_w * 8192;
  if (ci_w < 2) {
    const float sc = (ci_w == 0) ? SCALE_Q : 1.f;
#pragma unroll
    for (int mi = 0; mi < 4; ++mi) {
      int mg = m0 + wm + mi * 16 + quad * 4;
      float b0 = qkv_b[mg + 0], b1 = qkv_b[mg + 1];
      float b2 = qkv_b[mg + 2], b3 = qkv_b[mg + 3];
      int ch = mi * 16 + quad * 4;
#pragma unroll
      for (int ni = 0; ni < 4; ++ni) {
        int lloc = wn + ni * 16 + col;
        float v0 = (acc[mi][ni][0] + b0) * sc;
        float v1 = (acc[mi][ni][1] + b1) * sc;
        float v2 = (acc[mi][ni][2] + b2) * sc;
        float v3 = (acc[mi][ni][3] + b3) * sc;
        int chs = ch ^ ((lloc & 7) << 3);
        *(uint2*)&Tile[lloc * 64 + chs] =
            make_uint2(pack_bf2(v0, v1), pack_bf2(v2, v3));
      }
    }
  } else {
#pragma unroll
    for (int mi = 0; mi < 4; ++mi)
#pragma unroll
      for (int r = 0; r < 4; ++r) {
        int ch = mi * 16 + quad * 4 + r;
        float bias = qkv_b[m0 + wm + ch];
#pragma unroll
        for (int ni = 0; ni < 4; ++ni) {
          int lloc = wn + ni * 16 + col;
          Tile[ch * 128 + lloc] =
              (ushort_t)(__float_as_uint(acc[mi][ni][r] + bias) >> 16);
        }
      }
  }
  __syncthreads();
  const int head = blockIdx.y;
  const int bh = b * NH + head;
#pragma unroll
  for (int ci = 0; ci < 3; ++ci) {
    ushort_t* T2 = Smem + ci * 8192;
    if (ci < 2) {
      ushort_t* dst = (ci == 0) ? qT : kT;
#pragma unroll
      for (int it = 0; it < 3; ++it) {
        int idx = tid + it * 384;
        if (idx < 1024) {
          int l = idx >> 3, seg = idx & 7;
          uint4 v = *(const uint4*)&T2[l * 64 + seg * 8];
          *(uint4*)(dst + ((size_t)bh * LL + n0 + l) * CH + seg * 8) = v;
        }
      }
    } else {
#pragma unroll
      for (int it = 0; it < 3; ++it) {
        int idx = tid + it * 384;
        if (idx < 1024) {
          int ch = idx >> 4, lseg = idx & 15;
          uint4 v = *(const uint4*)&T2[ch * 128 + lseg * 8];
          int g = lseg & 7, blk = lseg >> 3;
          *(uint4*)(vbuf + ((size_t)bh * CH + ch) * LL + n0 + blk * 64 +
                    ((g ^ (ch & 7)) << 3)) = v;
        }
      }
    }
  }
}

// ---------------- Flash attention: 32x32 MFMA, 8 waves x 256 t rows --------
// One K/V staging pass now serves 256 t-rows: half the DMA issues, half the
// L2 K/V re-reads, half the barrier-iters per unit work vs the 4-wave form.
__global__ __launch_bounds__(512) void attn_mfma_kernel(
    const ushort_t* __restrict__ qT, const ushort_t* __restrict__ kT,
    const ushort_t* __restrict__ vbuf, ushort_t* __restrict__ abuf) {
  // XCD-aware swizzle: all 4 t-tiles of one bh to the same XCD (L2 reuse)
  const int Bx = blockIdx.x;
  const int bh = (Bx & 7) * 8 + ((Bx >> 3) >> 2);
  const int t0g = ((Bx >> 3) & 3) * 256;
  const int b = bh >> 3, h = bh & 7;
  const int tid = threadIdx.x;
  const int w = tid >> 6, lane = tid & 63;
  const int ln31 = lane & 31, hi = lane >> 5;
  __shared__ ushort_t Ksm[2][64 * 64];   // double-buffered K [s][c]
  __shared__ ushort_t Vsm[2][64 * 64];   // double-buffered V [c][s]

  const ushort_t* kbase = kT + (size_t)bh * LL * CH;
  const ushort_t* vbase = vbuf + (size_t)bh * CH * LL;
  const int eb = w * 512 + lane * 8;  // 8 waves cover one 4096-elt buffer

  // stage tile 0 (K: contiguous 8KB; V: 128B row segments)
  g2l16(kbase + eb, &Ksm[0][w * 512]);
  g2l16(vbase + (size_t)(eb >> 6) * LL + (eb & 63), &Vsm[0][w * 512]);
  // Q B-fragments: rows t = w*32+ln31, k-elems c = j*16 + hi*8 + 0..7
  const ushort_t* qtile = qT + ((size_t)bh * LL + t0g) * CH;
  short8 bq[4];
#pragma unroll
  for (int j = 0; j < 4; ++j)
    bq[j] = *(const short8*)&qtile[swz(w * 32 + ln31, j * 16 + hi * 8)];

  float m_s = 0.f, lsum = 0.f;
  f32x16 oacc[2];
  f32x16 zz = {0.f, 0.f, 0.f, 0.f, 0.f, 0.f, 0.f, 0.f,
               0.f, 0.f, 0.f, 0.f, 0.f, 0.f, 0.f, 0.f};
  oacc[0] = zz;
  oacc[1] = zz;
  __syncthreads();  // implicit vmcnt(0): buf0 staged

  int cur = 0;
  for (int it = 0; it < 16; ++it) {
    if (it < 15) {  // prefetch next tile; drained by end-of-iter barrier
      g2l16(kbase + (size_t)(it + 1) * 64 * CH + eb, &Ksm[cur ^ 1][w * 512]);
      g2l16(vbase + (size_t)(eb >> 6) * LL + (it + 1) * 64 + (eb & 63),
            &Vsm[cur ^ 1][w * 512]);
    }
    const ushort_t* Kc = Ksm[cur];
    const ushort_t* Vc = Vsm[cur];
    // S^T[s][t] = K Q^T (q pre-scaled by 0.125*log2e). Lane: t=ln31 (wave
    // strip), s = sq*32 + (r&3)+8*(r>>2)+4*hi.
    f32x16 sacc[2];
    sacc[0] = zz;
    sacc[1] = zz;
    __builtin_amdgcn_s_setprio(1);
#pragma unroll
    for (int sq = 0; sq < 2; ++sq)
#pragma unroll
      for (int j = 0; j < 4; ++j) {
        short8 ak = *(const short8*)&Kc[swz(sq * 32 + ln31, j * 16 + hi * 8)];
        sacc[sq] = __builtin_amdgcn_mfma_f32_32x32x16_bf16(ak, bq[j],
                                                           sacc[sq], 0, 0, 0);
      }
    __builtin_amdgcn_s_setprio(0);
    if (it == 0) {  // freeze softmax shift at tile-0 max (wave-uniform)
      float mx = sacc[0][0];
#pragma unroll
      for (int sq = 0; sq < 2; ++sq)
#pragma unroll
        for (int r = 0; r < 16; ++r) mx = fmaxf(mx, sacc[sq][r]);
#pragma unroll
      for (int off = 32; off > 0; off >>= 1) mx = fmaxf(mx, __shfl_xor(mx, off));
      m_s = mx;
    }
    // p = exp2(S' - m); pack to bf16; permlane32_swap exchanges s-halves so
    // each lane holds A-frag rows t=ln31, k-elems s = ks*16 + hi*8 + 0..7.
    short8 pf[4];
#pragma unroll
    for (int sq = 0; sq < 2; ++sq) {
      float p[16];
#pragma unroll
      for (int r = 0; r < 16; ++r) {
        p[r] = __builtin_amdgcn_exp2f(sacc[sq][r] - m_s);
        lsum += p[r];
      }
      unsigned d0[4], d1[4];
#pragma unroll
      for (int q = 0; q < 4; ++q) {
        d0[q] = pack_bf2(p[q * 4 + 0], p[q * 4 + 1]);
        d1[q] = pack_bf2(p[q * 4 + 2], p[q * 4 + 3]);
      }
#pragma unroll
      for (int m = 0; m < 2; ++m) {
        unsigned x0 = d0[m * 2], y0 = d0[m * 2 + 1];
        unsigned x1 = d1[m * 2], y1 = d1[m * 2 + 1];
        asm volatile("v_permlane32_swap_b32 %0, %1" : "+v"(x0), "+v"(y0));
        asm volatile("v_permlane32_swap_b32 %0, %1" : "+v"(x1), "+v"(y1));
        union { uint4 u; short8 s; } fu;
        fu.u = make_uint4(x0, x1, y0, y1);
        pf[sq * 2 + m] = fu.s;
      }
    }
    // O[t][c] += P V^T
    __builtin_amdgcn_s_setprio(1);
#pragma unroll
    for (int cq = 0; cq < 2; ++cq)
#pragma unroll
      for (int ks = 0; ks < 4; ++ks) {
        short8 bv = *(const short8*)&Vc[swz(cq * 32 + ln31, ks * 16 + hi * 8)];
        oacc[cq] = __builtin_amdgcn_mfma_f32_32x32x16_bf16(pf[ks], bv,
                                                           oacc[cq], 0, 0, 0);
      }
    __builtin_amdgcn_s_setprio(0);
    __syncthreads();  // implicit vmcnt(0): next buf staged, cur consumed
    cur ^= 1;
  }
  // row sums: lane has half-s sum for t = ln31; merge with partner half
  lsum += __shfl_xor(lsum, 32);
#pragma unroll
  for (int r = 0; r < 16; ++r) {
    int tl = (r & 3) + 8 * (r >> 2) + 4 * hi;  // output t within wave strip
    float li = 1.f / __shfl(lsum, tl, 64);
    int lg = t0g + w * 32 + tl;
#pragma unroll
    for (int cq = 0; cq < 2; ++cq) {
      int cl = cq * 32 + ln31;
      // pre-swizzled abuf image (proj stages it linearly via DMA)
      int dcol = ((((cl >> 3) ^ (lg & 7)) << 3) | (cl & 7));
      abuf[((size_t)b * LL + lg) * CC + h * CH + dcol] =
          f2bf(oacc[cq][r] * li);
    }
  }
}

// ---------------- proj GEMM + bias + residual: 2-phase dbuf DMA ------------
__global__ __launch_bounds__(256) void proj_mfma_kernel(
    const ushort_t* __restrict__ wp, const ushort_t* __restrict__ abuf,
    const float* __restrict__ proj_b, const float* __restrict__ x,
    float* __restrict__ out) {
  const int b = blockIdx.z;
  const int m0 = blockIdx.y * 64;
  const int n0 = blockIdx.x * 128;
  const int tid = threadIdx.x;
  const int w = tid >> 6, lane = tid & 63;
  const int col = lane & 15, quad = lane >> 4;
  const int wm = (w >> 1) * 32, wn = (w & 1) * 64;
  __shared__ ushort_t Smem[2 * 12288];
  f32x4 acc[2][4];
  f32x4 z = {0.f, 0.f, 0.f, 0.f};
#pragma unroll
  for (int i = 0; i < 2; ++i)
#pragma unroll
    for (int j = 0; j < 4; ++j) acc[i][j] = z;

  const ushort_t* arow = wp + (size_t)m0 * CC;
  const ushort_t* brow = abuf + ((size_t)b * LL + n0) * CC;

  auto stage = [&](int bb, int k0) {
    ushort_t* As = Smem + bb * 12288;
    ushort_t* Bs = As + 4096;
#pragma unroll
    for (int j = 0; j < 2; ++j) {
      int e = (j * 4 + w) * 512 + lane * 8;
      g2l16(arow + (size_t)(e >> 6) * CC + k0 + (e & 63),
            As + (j * 4 + w) * 512);
    }
#pragma unroll
    for (int j = 0; j < 4; ++j) {
      int e = (j * 4 + w) * 512 + lane * 8;
      g2l16(brow + (size_t)(e >> 6) * CC + k0 + (e & 63),
            Bs + (j * 4 + w) * 512);
    }
  };

  stage(0, 0);
  __syncthreads();
  int cur = 0;
  for (int step = 0; step < 8; ++step) {
    if (step < 7) stage(cur ^ 1, (step + 1) * 64);
    const ushort_t* As = Smem + cur * 12288;
    const ushort_t* Bs = As + 4096;
#pragma unroll
    for (int kk = 0; kk < 2; ++kk) {
      short8 af[2], bf[4];
#pragma unroll
      for (int mi = 0; mi < 2; ++mi)
        af[mi] = *(const short8*)&As[swz(wm + mi * 16 + col, kk * 32 + quad * 8)];
#pragma unroll
      for (int ni = 0; ni < 4; ++ni)
        bf[ni] = *(const short8*)&Bs[swz(wn + ni * 16 + col, kk * 32 + quad * 8)];
#pragma unroll
      for (int mi = 0; mi < 2; ++mi)
#pragma unroll
        for (int ni = 0; ni < 4; ++ni)
          acc[mi][ni] = __builtin_amdgcn_mfma_f32_16x16x32_bf16(
              af[mi], bf[ni], acc[mi][ni], 0, 0, 0);
    }
    __syncthreads();
    cur ^= 1;
  }
#pragma unroll
  for (int mi = 0; mi < 2; ++mi)
#pragma unroll
    for (int r = 0; r < 4; ++r) {
      int o = m0 + wm + mi * 16 + quad * 4 + r;
      float bias = proj_b[o];
#pragma unroll
      for (int ni = 0; ni < 4; ++ni) {
        int l = n0 + wn + ni * 16 + col;
        size_t off = ((size_t)b * CC + o) * LL + l;
        out[off] = x[off] + bias + acc[mi][ni][r];
      }
    }
}

extern "C" void kernel_launch(void* const* d_in, const int* in_sizes, int n_in,
                              void* d_out, int out_size, void* d_ws,
                              size_t ws_size, hipStream_t stream) {
  const float* x = (const float*)d_in[0];
  const float* gn_w = (const float*)d_in[1];
  const float* gn_b = (const float*)d_in[2];
  const float* qkv_w = (const float*)d_in[3];
  const float* qkv_b = (const float*)d_in[4];
  const float* proj_w = (const float*)d_in[5];
  const float* proj_b = (const float*)d_in[6];
  float* out = (float*)d_out;

  char* ws = (char*)d_ws;
  ushort_t* wq = (ushort_t*)ws;
  ushort_t* wp = wq + (size_t)3 * CC * CC;
  ushort_t* xnT = wp + (size_t)CC * CC;
  ushort_t* qT = xnT + (size_t)BB * LL * CC;
  ushort_t* kT = qT + (size_t)BB * NH * LL * CH;
  ushort_t* vb = kT + (size_t)BB * NH * LL * CH;
  ushort_t* abuf = vb + (size_t)BB * NH * LL * CH;

  gnx_kernel<<<BB * GG + 512, 512, 0, stream>>>(x, gn_w, gn_b, qkv_w, proj_w,
                                                xnT, wq, wp);
  qkv_mfma_kernel<<<dim3(LL / 128, 1536 / 192, BB), 384, 0, stream>>>(
      wq, xnT, qkv_b, qT, kT, vb);
  attn_mfma_kernel<<<dim3(256), 512, 0, stream>>>(qT, kT, vb, abuf);
  proj_mfma_kernel<<<dim3(LL / 128, CC / 64, BB), 256, 0, stream>>>(
      wp, abuf, proj_b, x, out);
}

// Round 5
// 138.170 us; speedup vs baseline: 1.0137x; 1.0137x over previous
//
#include <hip/hip_runtime.h>
#include <math.h>

#define BB 8
#define CC 512
#define LL 1024
#define GG 32
#define CPG 16
#define NH 8
#define CH 64

typedef unsigned short ushort_t;
typedef __attribute__((ext_vector_type(8))) short short8;
typedef __attribute__((ext_vector_type(4))) float f32x4;
typedef __attribute__((ext_vector_type(16))) float f32x16;

#define SCALE_Q 0.18033688f  // 0.125 * log2(e)

__device__ inline ushort_t f2bf(float f) {
  union { float f; unsigned u; } v;
  v.f = f;
  unsigned r = v.u + 0x7FFFu + ((v.u >> 16) & 1u);
  return (ushort_t)(r >> 16);
}

// pack two f32 -> two bf16 (truncate) in one v_perm_b32
__device__ inline unsigned pack_bf2(float lo, float hi) {
  return __builtin_amdgcn_perm(__float_as_uint(hi), __float_as_uint(lo),
                               0x07060302u);
}

// XOR-swizzled LDS index: rows of 64 bf16, 8-elt groups swizzled by row&7.
__device__ inline int swz(int r, int k) {
  return r * 64 + ((((k >> 3) ^ (r & 7)) << 3) | (k & 7));
}

// V-tile LDS index: rows of 128 bf16 (two 64-blocks, group ^= row&7 inside).
__device__ inline int vswz(int c, int s) {
  return c * 128 + (s & 64) + ((((s >> 3) & 7) ^ (c & 7)) << 3) + (s & 7);
}

// async 16B global->LDS (DMA). LDS dest = wave-uniform base + lane*16.
__device__ __forceinline__ void g2l16(const void* g, void* l) {
  __builtin_amdgcn_global_load_lds((const unsigned int*)g, (unsigned int*)l,
                                   16, 0, 0);
}

// ------- fused GroupNorm (stats + apply + transpose) AND weight convert ----
// blocks [0,256): one (b,g) each — x slice kept in registers between phases.
// blocks [256,768): fp32->bf16 convert of qkv_w/proj_w to pre-swizzled image.
__global__ __launch_bounds__(512) void gnx_kernel(
    const float* __restrict__ x, const float* __restrict__ gn_w,
    const float* __restrict__ gn_b, const float* __restrict__ qkv_w,
    const float* __restrict__ proj_w, ushort_t* __restrict__ xnT,
    ushort_t* __restrict__ wq, ushort_t* __restrict__ wp) {
  if (blockIdx.x < BB * GG) {
    const int b = blockIdx.x / GG;
    const int g = blockIdx.x % GG;
    const int tid = threadIdx.x;
    const int ch = tid >> 5;    // 0..15 channel within group
    const int lseg = tid & 31;  // 32-l segment
    __shared__ ushort_t Ts[1024 * 32];
    __shared__ float red[16];
    __shared__ float st[2];
    const float* xc = x + ((size_t)b * CC + (size_t)g * CPG + ch) * LL;
    float4 v[8];
    float sum = 0.f, sq = 0.f;
#pragma unroll
    for (int i = 0; i < 8; ++i) {
      v[i] = *(const float4*)(xc + lseg * 32 + i * 4);
      sum += (v[i].x + v[i].y) + (v[i].z + v[i].w);
      sq += (v[i].x * v[i].x + v[i].y * v[i].y) +
            (v[i].z * v[i].z + v[i].w * v[i].w);
    }
#pragma unroll
    for (int off = 32; off > 0; off >>= 1) {
      sum += __shfl_down(sum, off);
      sq += __shfl_down(sq, off);
    }
    const int wave = tid >> 6;
    if ((tid & 63) == 0) {
      red[wave] = sum;
      red[8 + wave] = sq;
    }
    __syncthreads();
    if (tid == 0) {
      float s = 0.f, q = 0.f;
#pragma unroll
      for (int i = 0; i < 8; ++i) {
        s += red[i];
        q += red[8 + i];
      }
      float mean = s * (1.f / (CPG * LL));
      float var = q * (1.f / (CPG * LL)) - mean * mean;
      st[0] = mean;
      st[1] = rsqrtf(var + 1e-5f);
    }
    __syncthreads();
    const int c = g * CPG + ch;
    const float sc = st[1] * gn_w[c];
    const float sh = gn_b[c] - st[0] * sc;
    const int chG = ch >> 3, ch7 = ch & 7;
#pragma unroll
    for (int i = 0; i < 8; ++i) {
      float vv[4] = {v[i].x, v[i].y, v[i].z, v[i].w};
#pragma unroll
      for (int j = 0; j < 4; ++j) {
        int l = lseg * 32 + i * 4 + j;
        int key = ((l >> 5) + (l >> 2)) & 3;
        int slot = (chG + key) & 3;
        Ts[l * 32 + slot * 8 + ch7] = f2bf(vv[j] * sc + sh);
      }
    }
    __syncthreads();
    const int cb64 = (g >> 2) * 64;
    const int grpb = (g & 3) * 2;
#pragma unroll
    for (int it = 0; it < 4; ++it) {
      int idx = tid + it * 512;
      int l = idx >> 1, gsel = idx & 1;
      int key = ((l >> 5) + (l >> 2)) & 3;
      int slot = (gsel + key) & 3;
      uint4 val = *(const uint4*)&Ts[l * 32 + slot * 8];
      int grp = (grpb + gsel) ^ (l & 7);
      *(uint4*)(xnT + ((size_t)b * LL + l) * CC + cb64 + grp * 8) = val;
    }
  } else {
    int cb = blockIdx.x - BB * GG;
    int idx = (cb * 512 + threadIdx.x) * 4;
    const int N1 = 3 * CC * CC;
    float4 v;
    ushort_t* mat;
    int row, k;
    if (idx < N1) {
      v = *(const float4*)(qkv_w + idx);
      row = idx >> 9;
      k = idx & 511;
      mat = wq + (size_t)row * CC;
    } else {
      int j = idx - N1;
      v = *(const float4*)(proj_w + j);
      row = j >> 9;
      k = j & 511;
      mat = wp + (size_t)row * CC;
    }
    int dcol = (k & ~63) | ((((k >> 3) & 7) ^ (row & 7)) << 3) | (k & 7);
    unsigned lo = f2bf(v.x) | ((unsigned)f2bf(v.y) << 16);
    unsigned hi = f2bf(v.z) | ((unsigned)f2bf(v.w) << 16);
    *(uint2*)(mat + dcol) = make_uint2(lo, hi);
  }
}

// ---------------- QKV GEMM: 192x128 tile, 6 waves, 2-phase dbuf DMA --------
__global__ __launch_bounds__(384, 3) void qkv_mfma_kernel(
    const ushort_t* __restrict__ wq, const ushort_t* __restrict__ xnT,
    const float* __restrict__ qkv_b, ushort_t* __restrict__ qT,
    ushort_t* __restrict__ kT, ushort_t* __restrict__ vbuf) {
  const int b = blockIdx.z;
  const int m0 = blockIdx.y * 192;
  const int n0 = blockIdx.x * 128;
  const int tid = threadIdx.x;
  const int w = tid >> 6, lane = tid & 63;
  const int col = lane & 15, quad = lane >> 4;
  const int wm = (w >> 1) * 64, wn = (w & 1) * 64;
  __shared__ ushort_t Smem[2 * 20480];
  f32x4 acc[4][4];
  f32x4 z = {0.f, 0.f, 0.f, 0.f};
#pragma unroll
  for (int i = 0; i < 4; ++i)
#pragma unroll
    for (int j = 0; j < 4; ++j) acc[i][j] = z;

  const ushort_t* arow = wq + (size_t)m0 * CC;
  const ushort_t* brow = xnT + ((size_t)b * LL + n0) * CC;

  auto stage = [&](int bb, int k0) {
    ushort_t* As = Smem + bb * 20480;
    ushort_t* Bs = As + 12288;
#pragma unroll
    for (int j = 0; j < 4; ++j) {
      int e = (j * 6 + w) * 512 + lane * 8;
      g2l16(arow + (size_t)(e >> 6) * CC + k0 + (e & 63),
            As + (j * 6 + w) * 512);
    }
    if (w < 4) {
#pragma unroll
      for (int j = 0; j < 4; ++j) {
        int e = (j * 4 + w) * 512 + lane * 8;
        g2l16(brow + (size_t)(e >> 6) * CC + k0 + (e & 63),
              Bs + (j * 4 + w) * 512);
      }
    }
  };

  stage(0, 0);
  __syncthreads();
  int cur = 0;
  for (int step = 0; step < 8; ++step) {
    if (step < 7) stage(cur ^ 1, (step + 1) * 64);
    const ushort_t* As = Smem + cur * 20480;
    const ushort_t* Bs = As + 12288;
#pragma unroll
    for (int kk = 0; kk < 2; ++kk) {
      short8 af[4], bf[4];
#pragma unroll
      for (int mi = 0; mi < 4; ++mi)
        af[mi] = *(const short8*)&As[swz(wm + mi * 16 + col, kk * 32 + quad * 8)];
#pragma unroll
      for (int ni = 0; ni < 4; ++ni)
        bf[ni] = *(const short8*)&Bs[swz(wn + ni * 16 + col, kk * 32 + quad * 8)];
#pragma unroll
      for (int mi = 0; mi < 4; ++mi)
#pragma unroll
        for (int ni = 0; ni < 4; ++ni)
          acc[mi][ni] = __builtin_amdgcn_mfma_f32_16x16x32_bf16(
              af[mi], bf[ni], acc[mi][ni], 0, 0, 0);
    }
    __syncthreads();
    cur ^= 1;
  }
  // ---- epilogue: wave pair (w>>1) writes chunk ci = w>>1 (0=q,1=k,2=v) ----
  const int ci_w = w >> 1;
  ushort_t* Tile = Smem + ci_w * 8192;
  if (ci_w < 2) {
    const float sc = (ci_w == 0) ? SCALE_Q : 1.f;
#pragma unroll
    for (int mi = 0; mi < 4; ++mi) {
      int mg = m0 + wm + mi * 16 + quad * 4;
      float b0 = qkv_b[mg + 0], b1 = qkv_b[mg + 1];
      float b2 = qkv_b[mg + 2], b3 = qkv_b[mg + 3];
      int ch = mi * 16 + quad * 4;
#pragma unroll
      for (int ni = 0; ni < 4; ++ni) {
        int lloc = wn + ni * 16 + col;
        float v0 = (acc[mi][ni][0] + b0) * sc;
        float v1 = (acc[mi][ni][1] + b1) * sc;
        float v2 = (acc[mi][ni][2] + b2) * sc;
        float v3 = (acc[mi][ni][3] + b3) * sc;
        int chs = ch ^ ((lloc & 7) << 3);
        *(uint2*)&Tile[lloc * 64 + chs] =
            make_uint2(pack_bf2(v0, v1), pack_bf2(v2, v3));
      }
    }
  } else {
#pragma unroll
    for (int mi = 0; mi < 4; ++mi)
#pragma unroll
      for (int r = 0; r < 4; ++r) {
        int ch = mi * 16 + quad * 4 + r;
        float bias = qkv_b[m0 + wm + ch];
#pragma unroll
        for (int ni = 0; ni < 4; ++ni) {
          int lloc = wn + ni * 16 + col;
          Tile[ch * 128 + lloc] =
              (ushort_t)(__float_as_uint(acc[mi][ni][r] + bias) >> 16);
        }
      }
  }
  __syncthreads();
  const int head = blockIdx.y;
  const int bh = b * NH + head;
#pragma unroll
  for (int ci = 0; ci < 3; ++ci) {
    ushort_t* T2 = Smem + ci * 8192;
    if (ci < 2) {
      ushort_t* dst = (ci == 0) ? qT : kT;
#pragma unroll
      for (int it = 0; it < 3; ++it) {
        int idx = tid + it * 384;
        if (idx < 1024) {
          int l = idx >> 3, seg = idx & 7;
          uint4 v = *(const uint4*)&T2[l * 64 + seg * 8];
          *(uint4*)(dst + ((size_t)bh * LL + n0 + l) * CH + seg * 8) = v;
        }
      }
    } else {
#pragma unroll
      for (int it = 0; it < 3; ++it) {
        int idx = tid + it * 384;
        if (idx < 1024) {
          int ch = idx >> 4, lseg = idx & 15;
          uint4 v = *(const uint4*)&T2[ch * 128 + lseg * 8];
          int g = lseg & 7, blk = lseg >> 3;
          *(uint4*)(vbuf + ((size_t)bh * CH + ch) * LL + n0 + blk * 64 +
                    ((g ^ (ch & 7)) << 3)) = v;
        }
      }
    }
  }
}

// ------- Flash attention: 32x32 MFMA, 4 waves x 128 t, KVBLK=128 ----------
// One stage+barrier serves two 64-s compute halves (8 barrier-iters total).
// Row sums accumulated on the MATRIX pipe via a ones-B MFMA (osum), killing
// the VALU lsum adds and the end-of-kernel shuffle reduction entirely.
__global__ __launch_bounds__(256) void attn_mfma_kernel(
    const ushort_t* __restrict__ qT, const ushort_t* __restrict__ kT,
    const ushort_t* __restrict__ vbuf, ushort_t* __restrict__ abuf) {
  // XCD-aware swizzle: all 8 t-tiles of one bh to the same XCD (L2 reuse)
  const int Bx = blockIdx.x;
  const int bh = (Bx & 7) * 8 + ((Bx >> 3) >> 3);
  const int t0g = ((Bx >> 3) & 7) * 128;
  const int b = bh >> 3, h = bh & 7;
  const int tid = threadIdx.x;
  const int w = tid >> 6, lane = tid & 63;
  const int ln31 = lane & 31, hi = lane >> 5;
  __shared__ ushort_t Ksm[2][128 * 64];  // K [s 128][c 64], swz rows
  __shared__ ushort_t Vsm[2][64 * 128];  // V [c 64][s 128], vswz rows

  const ushort_t* kbase = kT + (size_t)bh * LL * CH;
  const ushort_t* vbase = vbuf + (size_t)bh * CH * LL;

  // stage tile 0 (K: contiguous 16KB; V: 64 rows x 256B)
#pragma unroll
  for (int i = 0; i < 4; ++i) {
    int e = i * 2048 + w * 512 + lane * 8;
    g2l16(kbase + e, &Ksm[0][i * 2048 + w * 512]);
    g2l16(vbase + (size_t)(e >> 7) * LL + (e & 127),
          &Vsm[0][i * 2048 + w * 512]);
  }
  // Q B-fragments: rows t = w*32+ln31, k-elems c = j*16 + hi*8 + 0..7
  const ushort_t* qtile = qT + ((size_t)bh * LL + t0g) * CH;
  short8 bq[4];
#pragma unroll
  for (int j = 0; j < 4; ++j)
    bq[j] = *(const short8*)&qtile[swz(w * 32 + ln31, j * 16 + hi * 8)];

  // bf16 1.0 x8 for the row-sum MFMA
  union { unsigned u[4]; short8 s; } onesu;
#pragma unroll
  for (int i = 0; i < 4; ++i) onesu.u[i] = 0x3F803F80u;
  const short8 bones = onesu.s;

  float m_s = 0.f;
  f32x16 oacc[2], osum;
  f32x16 zz = {0.f, 0.f, 0.f, 0.f, 0.f, 0.f, 0.f, 0.f,
               0.f, 0.f, 0.f, 0.f, 0.f, 0.f, 0.f, 0.f};
  oacc[0] = zz;
  oacc[1] = zz;
  osum = zz;
  __syncthreads();  // implicit vmcnt(0): buf0 staged

  int cur = 0;
  for (int it2 = 0; it2 < 8; ++it2) {
    if (it2 < 7) {  // prefetch next 128-tile; drained by end-of-iter barrier
#pragma unroll
      for (int i = 0; i < 4; ++i) {
        int e = i * 2048 + w * 512 + lane * 8;
        g2l16(kbase + (size_t)(it2 + 1) * 8192 + e,
              &Ksm[cur ^ 1][i * 2048 + w * 512]);
        g2l16(vbase + (size_t)(e >> 7) * LL + (it2 + 1) * 128 + (e & 127),
              &Vsm[cur ^ 1][i * 2048 + w * 512]);
      }
    }
    const ushort_t* Kc = Ksm[cur];
    const ushort_t* Vc = Vsm[cur];
#pragma unroll
    for (int h2 = 0; h2 < 2; ++h2) {
      // S^T[s][t] = K Q^T (q pre-scaled by 0.125*log2e)
      f32x16 sacc[2];
      sacc[0] = zz;
      sacc[1] = zz;
      __builtin_amdgcn_s_setprio(1);
#pragma unroll
      for (int sq = 0; sq < 2; ++sq)
#pragma unroll
        for (int j = 0; j < 4; ++j) {
          short8 ak = *(const short8*)&Kc[swz(h2 * 64 + sq * 32 + ln31,
                                              j * 16 + hi * 8)];
          sacc[sq] = __builtin_amdgcn_mfma_f32_32x32x16_bf16(ak, bq[j],
                                                             sacc[sq], 0, 0, 0);
        }
      __builtin_amdgcn_s_setprio(0);
      if (it2 == 0 && h2 == 0) {  // freeze softmax shift at tile-0 max
        float mx = sacc[0][0];
#pragma unroll
        for (int sq = 0; sq < 2; ++sq)
#pragma unroll
          for (int r = 0; r < 16; ++r) mx = fmaxf(mx, sacc[sq][r]);
#pragma unroll
        for (int off = 32; off > 0; off >>= 1)
          mx = fmaxf(mx, __shfl_xor(mx, off));
        m_s = mx;
      }
      // p = exp2(S' - m); pack; permlane32_swap -> PV A-fragments in-register
      short8 pf[4];
#pragma unroll
      for (int sq = 0; sq < 2; ++sq) {
        float p[16];
#pragma unroll
        for (int r = 0; r < 16; ++r)
          p[r] = __builtin_amdgcn_exp2f(sacc[sq][r] - m_s);
        unsigned d0[4], d1[4];
#pragma unroll
        for (int q = 0; q < 4; ++q) {
          d0[q] = pack_bf2(p[q * 4 + 0], p[q * 4 + 1]);
          d1[q] = pack_bf2(p[q * 4 + 2], p[q * 4 + 3]);
        }
#pragma unroll
        for (int m = 0; m < 2; ++m) {
          unsigned x0 = d0[m * 2], y0 = d0[m * 2 + 1];
          unsigned x1 = d1[m * 2], y1 = d1[m * 2 + 1];
          asm volatile("v_permlane32_swap_b32 %0, %1" : "+v"(x0), "+v"(y0));
          asm volatile("v_permlane32_swap_b32 %0, %1" : "+v"(x1), "+v"(y1));
          union { uint4 u; short8 s; } fu;
          fu.u = make_uint4(x0, x1, y0, y1);
          pf[sq * 2 + m] = fu.s;
        }
      }
      // O[t][c] += P V^T ; row-sums on matrix pipe: osum += P * ones
      __builtin_amdgcn_s_setprio(1);
#pragma unroll
      for (int cq = 0; cq < 2; ++cq)
#pragma unroll
        for (int ks = 0; ks < 4; ++ks) {
          short8 bv = *(const short8*)&Vc[vswz(cq * 32 + ln31,
                                               h2 * 64 + ks * 16 + hi * 8)];
          oacc[cq] = __builtin_amdgcn_mfma_f32_32x32x16_bf16(pf[ks], bv,
                                                             oacc[cq], 0, 0, 0);
        }
#pragma unroll
      for (int ks = 0; ks < 4; ++ks)
        osum = __builtin_amdgcn_mfma_f32_32x32x16_bf16(pf[ks], bones, osum,
                                                       0, 0, 0);
      __builtin_amdgcn_s_setprio(0);
    }
    __syncthreads();  // implicit vmcnt(0): next buf staged, cur consumed
    cur ^= 1;
  }
  // osum[r] (any column) = full row sum for t-row tl(r); no cross-lane needed
#pragma unroll
  for (int r = 0; r < 16; ++r) {
    int tl = (r & 3) + 8 * (r >> 2) + 4 * hi;  // output t within wave strip
    float li = 1.f / osum[r];
    int lg = t0g + w * 32 + tl;
#pragma unroll
    for (int cq = 0; cq < 2; ++cq) {
      int cl = cq * 32 + ln31;
      // pre-swizzled abuf image (proj stages it linearly via DMA)
      int dcol = ((((cl >> 3) ^ (lg & 7)) << 3) | (cl & 7));
      abuf[((size_t)b * LL + lg) * CC + h * CH + dcol] =
          f2bf(oacc[cq][r] * li);
    }
  }
}

// ---------------- proj GEMM + bias + residual: 2-phase dbuf DMA ------------
__global__ __launch_bounds__(256) void proj_mfma_kernel(
    const ushort_t* __restrict__ wp, const ushort_t* __restrict__ abuf,
    const float* __restrict__ proj_b, const float* __restrict__ x,
    float* __restrict__ out) {
  const int b = blockIdx.z;
  const int m0 = blockIdx.y * 64;
  const int n0 = blockIdx.x * 128;
  const int tid = threadIdx.x;
  const int w = tid >> 6, lane = tid & 63;
  const int col = lane & 15, quad = lane >> 4;
  const int wm = (w >> 1) * 32, wn = (w & 1) * 64;
  __shared__ ushort_t Smem[2 * 12288];
  f32x4 acc[2][4];
  f32x4 z = {0.f, 0.f, 0.f, 0.f};
#pragma unroll
  for (int i = 0; i < 2; ++i)
#pragma unroll
    for (int j = 0; j < 4; ++j) acc[i][j] = z;

  const ushort_t* arow = wp + (size_t)m0 * CC;
  const ushort_t* brow = abuf + ((size_t)b * LL + n0) * CC;

  auto stage = [&](int bb, int k0) {
    ushort_t* As = Smem + bb * 12288;
    ushort_t* Bs = As + 4096;
#pragma unroll
    for (int j = 0; j < 2; ++j) {
      int e = (j * 4 + w) * 512 + lane * 8;
      g2l16(arow + (size_t)(e >> 6) * CC + k0 + (e & 63),
            As + (j * 4 + w) * 512);
    }
#pragma unroll
    for (int j = 0; j < 4; ++j) {
      int e = (j * 4 + w) * 512 + lane * 8;
      g2l16(brow + (size_t)(e >> 6) * CC + k0 + (e & 63),
            Bs + (j * 4 + w) * 512);
    }
  };

  stage(0, 0);
  __syncthreads();
  int cur = 0;
  for (int step = 0; step < 8; ++step) {
    if (step < 7) stage(cur ^ 1, (step + 1) * 64);
    const ushort_t* As = Smem + cur * 12288;
    const ushort_t* Bs = As + 4096;
#pragma unroll
    for (int kk = 0; kk < 2; ++kk) {
      short8 af[2], bf[4];
#pragma unroll
      for (int mi = 0; mi < 2; ++mi)
        af[mi] = *(const short8*)&As[swz(wm + mi * 16 + col, kk * 32 + quad * 8)];
#pragma unroll
      for (int ni = 0; ni < 4; ++ni)
        bf[ni] = *(const short8*)&Bs[swz(wn + ni * 16 + col, kk * 32 + quad * 8)];
#pragma unroll
      for (int mi = 0; mi < 2; ++mi)
#pragma unroll
        for (int ni = 0; ni < 4; ++ni)
          acc[mi][ni] = __builtin_amdgcn_mfma_f32_16x16x32_bf16(
              af[mi], bf[ni], acc[mi][ni], 0, 0, 0);
    }
    __syncthreads();
    cur ^= 1;
  }
#pragma unroll
  for (int mi = 0; mi < 2; ++mi)
#pragma unroll
    for (int r = 0; r < 4; ++r) {
      int o = m0 + wm + mi * 16 + quad * 4 + r;
      float bias = proj_b[o];
#pragma unroll
      for (int ni = 0; ni < 4; ++ni) {
        int l = n0 + wn + ni * 16 + col;
        size_t off = ((size_t)b * CC + o) * LL + l;
        out[off] = x[off] + bias + acc[mi][ni][r];
      }
    }
}

extern "C" void kernel_launch(void* const* d_in, const int* in_sizes, int n_in,
                              void* d_out, int out_size, void* d_ws,
                              size_t ws_size, hipStream_t stream) {
  const float* x = (const float*)d_in[0];
  const float* gn_w = (const float*)d_in[1];
  const float* gn_b = (const float*)d_in[2];
  const float* qkv_w = (const float*)d_in[3];
  const float* qkv_b = (const float*)d_in[4];
  const float* proj_w = (const float*)d_in[5];
  const float* proj_b = (const float*)d_in[6];
  float* out = (float*)d_out;

  char* ws = (char*)d_ws;
  ushort_t* wq = (ushort_t*)ws;
  ushort_t* wp = wq + (size_t)3 * CC * CC;
  ushort_t* xnT = wp + (size_t)CC * CC;
  ushort_t* qT = xnT + (size_t)BB * LL * CC;
  ushort_t* kT = qT + (size_t)BB * NH * LL * CH;
  ushort_t* vb = kT + (size_t)BB * NH * LL * CH;
  ushort_t* abuf = vb + (size_t)BB * NH * LL * CH;

  gnx_kernel<<<BB * GG + 512, 512, 0, stream>>>(x, gn_w, gn_b, qkv_w, proj_w,
                                                xnT, wq, wp);
  qkv_mfma_kernel<<<dim3(LL / 128, 1536 / 192, BB), 384, 0, stream>>>(
      wq, xnT, qkv_b, qT, kT, vb);
  attn_mfma_kernel<<<dim3(512), 256, 0, stream>>>(qT, kT, vb, abuf);
  proj_mfma_kernel<<<dim3(LL / 128, CC / 64, BB), 256, 0, stream>>>(
      wp, abuf, proj_b, x, out);
}